// Round 1
// baseline (1471.517 us; speedup 1.0000x reference)
//
#include <hip/hip_runtime.h>
#include <math.h>

#define KP 6
#define BATCH 256
#define DIM 768
#define NMEM 32768

// ---------------- norms (fp64 for rank stability) ----------------

__global__ __launch_bounds__(256) void norm_f_kernel(const float* __restrict__ F,
                                                     double* __restrict__ invF) {
  int row = blockIdx.x;  // 0 .. KP*BATCH-1
  const float* x = F + (size_t)row * DIM;
  int tid = threadIdx.x;
  double s = 0.0;
  for (int d = tid; d < DIM; d += 256) { double v = x[d]; s += v * v; }
  __shared__ double red[256];
  red[tid] = s; __syncthreads();
  for (int st = 128; st > 0; st >>= 1) {
    if (tid < st) red[tid] += red[tid + st];
    __syncthreads();
  }
  if (tid == 0) invF[row] = 1.0 / fmax(sqrt(red[0]), 1e-12);
}

__global__ __launch_bounds__(256) void norm_m_kernel(const float* __restrict__ M,
                                                     double* __restrict__ invM) {
  int wid = threadIdx.x >> 6, lane = threadIdx.x & 63;
  size_t row = (size_t)blockIdx.x * 4 + wid;  // 0 .. KP*NMEM-1
  const float* x = M + row * DIM;
  double s = 0.0;
  for (int d = lane; d < DIM; d += 64) { double v = x[d]; s += v * v; }
  for (int off = 32; off > 0; off >>= 1) s += __shfl_down(s, off);
  if (lane == 0) invM[row] = 1.0 / fmax(sqrt(s), 1e-12);
}

// ---------------- fp32 GEMM: sim[k,b,n] = <f_kb, m_kn> * invF * invM ----------------

#define BM 64
#define BN 64
#define BK 16

__global__ __launch_bounds__(256) void gemm_kernel(
    const float* __restrict__ F, const float* __restrict__ M,
    const double* __restrict__ invF, const double* __restrict__ invM,
    float* __restrict__ sim) {
  int k = blockIdx.z;
  int bm0 = blockIdx.y * BM;
  int bn0 = blockIdx.x * BN;
  const float* Fk = F + (size_t)k * BATCH * DIM;
  const float* Mk = M + (size_t)k * NMEM * DIM;
  __shared__ float As[BK][BM + 4];
  __shared__ float Bs[BK][BN + 4];
  int tid = threadIdx.x;
  int tx = tid & 15, ty = tid >> 4;
  int lrow = tid >> 2;          // 0..63
  int ld0 = (tid & 3) << 2;     // 0,4,8,12
  float acc[4][4] = {};
  for (int kk = 0; kk < DIM; kk += BK) {
    float4 av = *reinterpret_cast<const float4*>(Fk + (size_t)(bm0 + lrow) * DIM + kk + ld0);
    float4 bv = *reinterpret_cast<const float4*>(Mk + (size_t)(bn0 + lrow) * DIM + kk + ld0);
    As[ld0 + 0][lrow] = av.x; As[ld0 + 1][lrow] = av.y;
    As[ld0 + 2][lrow] = av.z; As[ld0 + 3][lrow] = av.w;
    Bs[ld0 + 0][lrow] = bv.x; Bs[ld0 + 1][lrow] = bv.y;
    Bs[ld0 + 2][lrow] = bv.z; Bs[ld0 + 3][lrow] = bv.w;
    __syncthreads();
#pragma unroll
    for (int kkk = 0; kkk < BK; ++kkk) {
      float4 a = *reinterpret_cast<const float4*>(&As[kkk][ty << 2]);
      float4 b = *reinterpret_cast<const float4*>(&Bs[kkk][tx << 2]);
      float ar[4] = {a.x, a.y, a.z, a.w};
      float br[4] = {b.x, b.y, b.z, b.w};
#pragma unroll
      for (int i = 0; i < 4; ++i)
#pragma unroll
        for (int j = 0; j < 4; ++j) acc[i][j] = fmaf(ar[i], br[j], acc[i][j]);
    }
    __syncthreads();
  }
  size_t kb = (size_t)k * BATCH;
  float im[4];
#pragma unroll
  for (int j = 0; j < 4; ++j)
    im[j] = (float)invM[(size_t)k * NMEM + bn0 + (tx << 2) + j];
#pragma unroll
  for (int i = 0; i < 4; ++i) {
    int r = bm0 + (ty << 2) + i;
    float fi = (float)invF[kb + r];
    float4 o = make_float4(acc[i][0] * fi * im[0], acc[i][1] * fi * im[1],
                           acc[i][2] * fi * im[2], acc[i][3] * fi * im[3]);
    *reinterpret_cast<float4*>(sim + (kb + r) * NMEM + bn0 + (tx << 2)) = o;
  }
}

// ---------------- top-k + fp64 refine + softmax scatter + entropy ----------------

__global__ __launch_bounds__(256) void topk_kernel(
    const float* __restrict__ F, const float* __restrict__ M,
    const double* __restrict__ invF, const double* __restrict__ invM,
    const float* __restrict__ sim, float* __restrict__ soft,
    float* __restrict__ ent) {
  int kb = blockIdx.x;  // k*BATCH + b
  int k = kb / BATCH;
  int tid = threadIdx.x;
  const float* srow = sim + (size_t)kb * NMEM;

  // per-thread top-8 (sorted ascending, static-indexed so it stays in VGPRs)
  float tv[8]; int ti[8];
#pragma unroll
  for (int j = 0; j < 8; ++j) { tv[j] = -INFINITY; ti[j] = -1; }
  for (int i = 0; i < NMEM / 256; ++i) {
    int n = (i << 8) + tid;
    float v = srow[n];
    if (v > tv[0]) {
      tv[0] = v; ti[0] = n;
#pragma unroll
      for (int j = 0; j < 7; ++j) {
        if (tv[j] > tv[j + 1]) {
          float t = tv[j]; tv[j] = tv[j + 1]; tv[j + 1] = t;
          int q = ti[j]; ti[j] = ti[j + 1]; ti[j + 1] = q;
        }
      }
    }
  }

  __shared__ float sval[2048];
  __shared__ int   sidx[2048];
#pragma unroll
  for (int j = 0; j < 8; ++j) { sval[tid * 8 + j] = tv[j]; sidx[tid * 8 + j] = ti[j]; }
  __syncthreads();

  __shared__ float rv[256]; __shared__ int rp[256];
  __shared__ float cand_v[8]; __shared__ int cand_i[8];
  for (int r = 0; r < 8; ++r) {
    float best = -INFINITY; int bpos = tid * 8;
#pragma unroll
    for (int j = 0; j < 8; ++j) {
      float v = sval[tid * 8 + j];
      if (v > best) { best = v; bpos = tid * 8 + j; }
    }
    rv[tid] = best; rp[tid] = bpos;
    __syncthreads();
    for (int st = 128; st > 0; st >>= 1) {
      if (tid < st && rv[tid + st] > rv[tid]) { rv[tid] = rv[tid + st]; rp[tid] = rp[tid + st]; }
      __syncthreads();
    }
    if (tid == 0) {
      cand_v[r] = rv[0]; cand_i[r] = sidx[rp[0]];
      sval[rp[0]] = -INFINITY;
    }
    __syncthreads();
  }

  // fp64 refinement of the 8 candidates (exact re-ranking at the 5/6 boundary)
  __shared__ double dred[256];
  __shared__ double cval[8];
  const float* fr = F + (size_t)kb * DIM;
  double invf = invF[kb];
  for (int c = 0; c < 8; ++c) {
    const float* mr = M + ((size_t)k * NMEM + cand_i[c]) * DIM;
    double s = 0.0;
    for (int d = tid; d < DIM; d += 256) s += (double)fr[d] * (double)mr[d];
    dred[tid] = s; __syncthreads();
    for (int st = 128; st > 0; st >>= 1) {
      if (tid < st) dred[tid] += dred[tid + st];
      __syncthreads();
    }
    if (tid == 0) cval[c] = dred[0] * invf * invM[(size_t)k * NMEM + cand_i[c]];
    __syncthreads();
  }

  if (tid == 0) {
    // rank by fp32-rounded refined value (matches ref's fp32 compare), tie -> lower index
    int ord[8];
    for (int i = 0; i < 8; ++i) ord[i] = i;
    for (int i = 0; i < 5; ++i) {
      int best = i;
      for (int j = i + 1; j < 8; ++j) {
        float fa = (float)cval[ord[j]], fb = (float)cval[ord[best]];
        bool better = false;
        if (fa != fb) better = (fa > fb);
        else better = (cand_i[ord[j]] < cand_i[ord[best]]);
        if (better) best = j;
      }
      int t = ord[i]; ord[i] = ord[best]; ord[best] = t;
    }
    float v5[5]; int i5[5];
    float vmax = -INFINITY;
    for (int i = 0; i < 5; ++i) {
      v5[i] = cand_v[ord[i]]; i5[i] = cand_i[ord[i]];
      vmax = fmaxf(vmax, v5[i]);
    }
    float e[5], Z = 0.f;
    float xm = vmax / 3.0f;
    for (int i = 0; i < 5; ++i) { e[i] = expf(v5[i] / 3.0f - xm); Z += e[i]; }
    float ent_s = 0.f;
    for (int i = 0; i < 5; ++i) {
      float p = e[i] / Z;
      soft[(size_t)kb * NMEM + i5[i]] = p;
      ent_s += p * logf(p);
    }
    float tiny = 1e-8f * logf(1e-8f);
    ent[kb] = -(ent_s + (float)(NMEM - 5) * tiny);
  }
}

// ---------------- entropy weights ----------------

__global__ __launch_bounds__(256) void w_kernel(const float* __restrict__ ent,
                                                float* __restrict__ wout) {
  int k = blockIdx.x; int tid = threadIdx.x;
  float e = ent[k * BATCH + tid];
  float wv = expf(-e);
  __shared__ float red[256];
  red[tid] = wv; __syncthreads();
  for (int st = 128; st > 0; st >>= 1) {
    if (tid < st) red[tid] += red[tid + st];
    __syncthreads();
  }
  float mean = red[0] / (float)BATCH;
  wout[k * BATCH + tid] = wv / (mean + 1e-8f);
}

// ---------------- launch ----------------

extern "C" void kernel_launch(void* const* d_in, const int* in_sizes, int n_in,
                              void* d_out, int out_size, void* d_ws, size_t ws_size,
                              hipStream_t stream) {
  (void)in_sizes; (void)n_in; (void)out_size; (void)ws_size;
  const float* F = (const float*)d_in[0];   // [KP, BATCH, DIM]
  const float* M = (const float*)d_in[1];   // [KP, NMEM, DIM]
  float* out = (float*)d_out;
  size_t simsz = (size_t)KP * BATCH * NMEM;
  float* soft = out;
  float* sim = out + simsz;
  float* wout = out + 2 * simsz;

  double* invF = (double*)d_ws;                       // KP*BATCH doubles
  double* invM = invF + KP * BATCH;                   // KP*NMEM doubles
  float* ent = (float*)(invM + (size_t)KP * NMEM);    // KP*BATCH floats

  hipMemsetAsync(soft, 0, simsz * sizeof(float), stream);
  norm_f_kernel<<<KP * BATCH, 256, 0, stream>>>(F, invF);
  norm_m_kernel<<<KP * NMEM / 4, 256, 0, stream>>>(M, invM);
  gemm_kernel<<<dim3(NMEM / BN, BATCH / BM, KP), 256, 0, stream>>>(F, M, invF, invM, sim);
  topk_kernel<<<KP * BATCH, 256, 0, stream>>>(F, M, invF, invM, sim, soft, ent);
  w_kernel<<<KP, 256, 0, stream>>>(ent, wout);
}

// Round 2
// 668.801 us; speedup vs baseline: 2.2002x; 2.2002x over previous
//
#include <hip/hip_runtime.h>
#include <math.h>

#define KP 6
#define BATCH 256
#define DIM 768
#define NMEM 32768

typedef __attribute__((ext_vector_type(8))) short bf16x8;
typedef __attribute__((ext_vector_type(4))) float f32x4;

__device__ inline uint bf16rne(float x) {
  uint u = __builtin_bit_cast(uint, x);
  return (u + 0x7fffu + ((u >> 16) & 1u)) >> 16;
}
__device__ inline uint pk2(float lo, float hi) {
  return bf16rne(lo) | (bf16rne(hi) << 16);
}
// XOR swizzle on 16B units keyed by row bits (row stride = 64B): involution.
__device__ inline int swz(int b) { return b ^ (((b >> 7) & 3) << 4); }

// ---------------- norms (fp64 for rank stability) ----------------

__global__ __launch_bounds__(256) void norm_f_kernel(const float* __restrict__ F,
                                                     double* __restrict__ invF) {
  int row = blockIdx.x;
  const float* x = F + (size_t)row * DIM;
  int tid = threadIdx.x;
  double s = 0.0;
  for (int d = tid; d < DIM; d += 256) { double v = x[d]; s += v * v; }
  __shared__ double red[256];
  red[tid] = s; __syncthreads();
  for (int st = 128; st > 0; st >>= 1) {
    if (tid < st) red[tid] += red[tid + st];
    __syncthreads();
  }
  if (tid == 0) invF[row] = 1.0 / fmax(sqrt(red[0]), 1e-12);
}

__global__ __launch_bounds__(256) void norm_m_kernel(const float* __restrict__ M,
                                                     double* __restrict__ invM) {
  int wid = threadIdx.x >> 6, lane = threadIdx.x & 63;
  size_t row = (size_t)blockIdx.x * 4 + wid;
  const float* x = M + row * DIM;
  double s = 0.0;
  for (int d = lane; d < DIM; d += 64) { double v = x[d]; s += v * v; }
  for (int off = 32; off > 0; off >>= 1) s += __shfl_down(s, off);
  if (lane == 0) invM[row] = 1.0 / fmax(sqrt(s), 1e-12);
}

// ---------------- bf16 MFMA GEMM: sim = (f·mT) * invF * invM ----------------
// 128x128 tile, BK=32, 4 waves (2x2), each wave 64x64 = 4x4 frags of 16x16x32.

#define GBM 128
#define GBN 128
#define GBK 32

__global__ __launch_bounds__(256) void gemm_bf16_kernel(
    const float* __restrict__ F, const float* __restrict__ M,
    const double* __restrict__ invF, const double* __restrict__ invM,
    float* __restrict__ sim) {
  int k = blockIdx.z;
  int bm0 = blockIdx.y * GBM;
  int bn0 = blockIdx.x * GBN;
  const float* Fk = F + (size_t)k * BATCH * DIM;
  const float* Mk = M + (size_t)k * NMEM * DIM;

  __shared__ __align__(16) ushort As[GBM * GBK];  // [row][k], 64B rows, swizzled
  __shared__ __align__(16) ushort Bs[GBN * GBK];
  char* AsB = (char*)As;
  char* BsB = (char*)Bs;

  int tid = threadIdx.x;
  int lane = tid & 63, wave = tid >> 6;
  int wr = (wave >> 1) * 64, wc = (wave & 1) * 64;

  // staging geometry: float4 index u = j*256 + tid; row = u>>3, c4 = u&7
  const float* gA[4]; const float* gB[4]; int wOff[4];
#pragma unroll
  for (int j = 0; j < 4; ++j) {
    int u = j * 256 + tid;
    int row = u >> 3, c4 = u & 7;
    gA[j] = Fk + (size_t)(bm0 + row) * DIM + c4 * 4;
    gB[j] = Mk + (size_t)(bn0 + row) * DIM + c4 * 4;
    wOff[j] = swz(row * 64 + c4 * 8);
  }
  // fragment read offsets (K-invariant)
  int l15 = lane & 15, lch = lane >> 4;
  int aoff[4], boff[4];
#pragma unroll
  for (int i = 0; i < 4; ++i) {
    aoff[i] = swz((wr + i * 16 + l15) * 64 + lch * 16);
    boff[i] = swz((wc + i * 16 + l15) * 64 + lch * 16);
  }

  f32x4 acc[4][4];
#pragma unroll
  for (int i = 0; i < 4; ++i)
#pragma unroll
    for (int j = 0; j < 4; ++j) acc[i][j] = (f32x4){0.f, 0.f, 0.f, 0.f};

  float4 pa[4], pb[4];
#pragma unroll
  for (int j = 0; j < 4; ++j) {
    pa[j] = *reinterpret_cast<const float4*>(gA[j]);
    pb[j] = *reinterpret_cast<const float4*>(gB[j]);
  }

  for (int kk = 0; kk < DIM; kk += GBK) {
    uint2 wa[4], wb[4];
#pragma unroll
    for (int j = 0; j < 4; ++j) {
      wa[j].x = pk2(pa[j].x, pa[j].y); wa[j].y = pk2(pa[j].z, pa[j].w);
      wb[j].x = pk2(pb[j].x, pb[j].y); wb[j].y = pk2(pb[j].z, pb[j].w);
    }
    __syncthreads();  // prior iteration's ds_reads complete
#pragma unroll
    for (int j = 0; j < 4; ++j) {
      *reinterpret_cast<uint2*>(AsB + wOff[j]) = wa[j];
      *reinterpret_cast<uint2*>(BsB + wOff[j]) = wb[j];
    }
    __syncthreads();  // tiles ready

    bf16x8 af[4], bfr[4];
#pragma unroll
    for (int i = 0; i < 4; ++i) {
      af[i] = *reinterpret_cast<const bf16x8*>(AsB + aoff[i]);
      bfr[i] = *reinterpret_cast<const bf16x8*>(BsB + boff[i]);
    }
    if (kk + GBK < DIM) {  // prefetch next K-step; overlaps MFMAs below
      int nk = kk + GBK;
#pragma unroll
      for (int j = 0; j < 4; ++j) {
        pa[j] = *reinterpret_cast<const float4*>(gA[j] + nk);
        pb[j] = *reinterpret_cast<const float4*>(gB[j] + nk);
      }
    }
#pragma unroll
    for (int i = 0; i < 4; ++i)
#pragma unroll
      for (int j = 0; j < 4; ++j)
        acc[i][j] = __builtin_amdgcn_mfma_f32_16x16x32_bf16(af[i], bfr[j], acc[i][j], 0, 0, 0);
  }

  // epilogue: D frag: col = lane&15, row = (lane>>4)*4 + reg
  size_t kb = (size_t)k * BATCH;
  int rgrp = lch << 2;
  float fi[4][4];
#pragma unroll
  for (int i = 0; i < 4; ++i)
#pragma unroll
    for (int r = 0; r < 4; ++r)
      fi[i][r] = (float)invF[kb + bm0 + wr + i * 16 + rgrp + r];
#pragma unroll
  for (int j = 0; j < 4; ++j) {
    int c = bn0 + wc + j * 16 + l15;
    float im = (float)invM[(size_t)k * NMEM + c];
#pragma unroll
    for (int i = 0; i < 4; ++i) {
      int rbase = bm0 + wr + i * 16 + rgrp;
#pragma unroll
      for (int r = 0; r < 4; ++r)
        sim[(kb + rbase + r) * NMEM + c] = acc[i][j][r] * fi[i][r] * im;
    }
  }
}

// ---------------- top-k + fp64 refine + softmax scatter + entropy ----------------

__global__ __launch_bounds__(256) void topk_kernel(
    const float* __restrict__ F, const float* __restrict__ M,
    const double* __restrict__ invF, const double* __restrict__ invM,
    const float* __restrict__ sim, float* __restrict__ soft,
    float* __restrict__ ent) {
  int kb = blockIdx.x;
  int k = kb / BATCH;
  int tid = threadIdx.x;
  const float* srow = sim + (size_t)kb * NMEM;
  float* orow = soft + (size_t)kb * NMEM;

  float tv[8]; int ti[8];
#pragma unroll
  for (int j = 0; j < 8; ++j) { tv[j] = -INFINITY; ti[j] = -1; }
  for (int i = 0; i < NMEM / 256; ++i) {
    int n = (i << 8) + tid;
    float v = srow[n];
    orow[n] = 0.f;  // fused zero-fill (replaces memset dispatch)
    if (v > tv[0]) {
      tv[0] = v; ti[0] = n;
#pragma unroll
      for (int j = 0; j < 7; ++j) {
        if (tv[j] > tv[j + 1]) {
          float t = tv[j]; tv[j] = tv[j + 1]; tv[j + 1] = t;
          int q = ti[j]; ti[j] = ti[j + 1]; ti[j + 1] = q;
        }
      }
    }
  }

  __shared__ float sval[2048];
  __shared__ int   sidx[2048];
#pragma unroll
  for (int j = 0; j < 8; ++j) { sval[tid * 8 + j] = tv[j]; sidx[tid * 8 + j] = ti[j]; }
  __syncthreads();

  __shared__ float rv[256]; __shared__ int rp[256];
  __shared__ float cand_v[8]; __shared__ int cand_i[8];
  for (int r = 0; r < 8; ++r) {
    float best = -INFINITY; int bpos = tid * 8;
#pragma unroll
    for (int j = 0; j < 8; ++j) {
      float v = sval[tid * 8 + j];
      if (v > best) { best = v; bpos = tid * 8 + j; }
    }
    rv[tid] = best; rp[tid] = bpos;
    __syncthreads();
    for (int st = 128; st > 0; st >>= 1) {
      if (tid < st && rv[tid + st] > rv[tid]) { rv[tid] = rv[tid + st]; rp[tid] = rp[tid + st]; }
      __syncthreads();
    }
    if (tid == 0) {
      cand_v[r] = rv[0]; cand_i[r] = sidx[rp[0]];
      sval[rp[0]] = -INFINITY;
    }
    __syncthreads();
  }

  // fp64 refinement of the 8 candidates (exact re-ranking at the 5/6 boundary)
  __shared__ double dred[256];
  __shared__ double cval[8];
  const float* fr = F + (size_t)kb * DIM;
  double invf = invF[kb];
  for (int c = 0; c < 8; ++c) {
    const float* mr = M + ((size_t)k * NMEM + cand_i[c]) * DIM;
    double s = 0.0;
    for (int d = tid; d < DIM; d += 256) s += (double)fr[d] * (double)mr[d];
    dred[tid] = s; __syncthreads();
    for (int st = 128; st > 0; st >>= 1) {
      if (tid < st) dred[tid] += dred[tid + st];
      __syncthreads();
    }
    if (tid == 0) cval[c] = dred[0] * invf * invM[(size_t)k * NMEM + cand_i[c]];
    __syncthreads();
  }

  if (tid == 0) {
    int ord[8];
    for (int i = 0; i < 8; ++i) ord[i] = i;
    for (int i = 0; i < 5; ++i) {
      int best = i;
      for (int j = i + 1; j < 8; ++j) {
        float fa = (float)cval[ord[j]], fb = (float)cval[ord[best]];
        bool better = (fa != fb) ? (fa > fb) : (cand_i[ord[j]] < cand_i[ord[best]]);
        if (better) best = j;
      }
      int t = ord[i]; ord[i] = ord[best]; ord[best] = t;
    }
    float v5[5]; int i5[5];
    float vmax = -INFINITY;
    for (int i = 0; i < 5; ++i) {
      v5[i] = cand_v[ord[i]]; i5[i] = cand_i[ord[i]];
      vmax = fmaxf(vmax, v5[i]);
    }
    float e[5], Z = 0.f;
    float xm = vmax / 3.0f;
    for (int i = 0; i < 5; ++i) { e[i] = expf(v5[i] / 3.0f - xm); Z += e[i]; }
    float ent_s = 0.f;
    for (int i = 0; i < 5; ++i) {
      float p = e[i] / Z;
      orow[i5[i]] = p;
      ent_s += p * logf(p);
    }
    float tiny = 1e-8f * logf(1e-8f);
    ent[kb] = -(ent_s + (float)(NMEM - 5) * tiny);
  }
}

// ---------------- entropy weights ----------------

__global__ __launch_bounds__(256) void w_kernel(const float* __restrict__ ent,
                                                float* __restrict__ wout) {
  int k = blockIdx.x; int tid = threadIdx.x;
  float e = ent[k * BATCH + tid];
  float wv = expf(-e);
  __shared__ float red[256];
  red[tid] = wv; __syncthreads();
  for (int st = 128; st > 0; st >>= 1) {
    if (tid < st) red[tid] += red[tid + st];
    __syncthreads();
  }
  float mean = red[0] / (float)BATCH;
  wout[k * BATCH + tid] = wv / (mean + 1e-8f);
}

// ---------------- launch ----------------

extern "C" void kernel_launch(void* const* d_in, const int* in_sizes, int n_in,
                              void* d_out, int out_size, void* d_ws, size_t ws_size,
                              hipStream_t stream) {
  (void)in_sizes; (void)n_in; (void)out_size; (void)ws_size;
  const float* F = (const float*)d_in[0];   // [KP, BATCH, DIM]
  const float* M = (const float*)d_in[1];   // [KP, NMEM, DIM]
  float* out = (float*)d_out;
  size_t simsz = (size_t)KP * BATCH * NMEM;
  float* soft = out;
  float* sim = out + simsz;
  float* wout = out + 2 * simsz;

  double* invF = (double*)d_ws;
  double* invM = invF + KP * BATCH;
  float* ent = (float*)(invM + (size_t)KP * NMEM);

  norm_f_kernel<<<KP * BATCH, 256, 0, stream>>>(F, invF);
  norm_m_kernel<<<KP * NMEM / 4, 256, 0, stream>>>(M, invM);
  gemm_bf16_kernel<<<dim3(NMEM / GBN, BATCH / GBM, KP), 256, 0, stream>>>(F, M, invF, invM, sim);
  topk_kernel<<<KP * BATCH, 256, 0, stream>>>(F, M, invF, invM, sim, soft, ent);
  w_kernel<<<KP, 256, 0, stream>>>(ent, wout);
}

// Round 3
// 489.819 us; speedup vs baseline: 3.0042x; 1.3654x over previous
//
#include <hip/hip_runtime.h>
#include <math.h>

#define KP 6
#define BATCH 256
#define DIM 768
#define NMEM 32768

typedef __attribute__((ext_vector_type(8))) short bf16x8;
typedef __attribute__((ext_vector_type(4))) float f32x4;

__device__ inline uint bf16rne(float x) {
  uint u = __builtin_bit_cast(uint, x);
  return (u + 0x7fffu + ((u >> 16) & 1u)) >> 16;
}
__device__ inline uint pk2(float lo, float hi) {
  return bf16rne(lo) | (bf16rne(hi) << 16);
}

__device__ inline void gld_lds16(const ushort* g, ushort* l) {
  __builtin_amdgcn_global_load_lds(
      (const __attribute__((address_space(1))) void*)g,
      (__attribute__((address_space(3))) void*)l, 16, 0, 0);
}

// ---------------- prep: fp64 inv-norms + bf16 copies ----------------
// one wave per row; 768 floats = 3 iters of float4/lane; bf16 written as uint2.

__global__ __launch_bounds__(256) void prep_kernel(const float* __restrict__ X,
                                                   ushort* __restrict__ Xb,
                                                   double* __restrict__ invX,
                                                   int nrows) {
  int wid = threadIdx.x >> 6, lane = threadIdx.x & 63;
  int row = blockIdx.x * 4 + wid;
  if (row >= nrows) return;
  const float* x = X + (size_t)row * DIM;
  ushort* xb = Xb + (size_t)row * DIM;
  double s = 0.0;
#pragma unroll
  for (int i = 0; i < 3; ++i) {
    int d = i * 256 + lane * 4;
    float4 v = *reinterpret_cast<const float4*>(x + d);
    s += (double)v.x * v.x + (double)v.y * v.y;
    s += (double)v.z * v.z + (double)v.w * v.w;
    uint2 p; p.x = pk2(v.x, v.y); p.y = pk2(v.z, v.w);
    *reinterpret_cast<uint2*>(xb + d) = p;
  }
  for (int off = 32; off > 0; off >>= 1) s += __shfl_down(s, off);
  if (lane == 0) invX[row] = 1.0 / fmax(sqrt(s), 1e-12);
}

// ---------------- bf16 MFMA GEMM (m97 structure): sim = (f·mT)*invF*invM ----
// 128x128 tile, BK=32, 4 waves (2x2), global_load_lds width-16 staging.

#define GBM 128
#define GBN 128
#define GBK 32

__global__ __launch_bounds__(256) void gemm_kernel(
    const ushort* __restrict__ Fb, const ushort* __restrict__ Mb,
    const double* __restrict__ invF, const double* __restrict__ invM,
    float* __restrict__ sim) {
  int k = blockIdx.z;
  int bm0 = blockIdx.y * GBM;
  int bn0 = blockIdx.x * GBN;
  const ushort* Fk = Fb + (size_t)k * BATCH * DIM;
  const ushort* Mk = Mb + (size_t)k * NMEM * DIM;

  __shared__ __align__(16) ushort As[GBM * GBK];  // [row][k] linear (gload_lds order)
  __shared__ __align__(16) ushort Bs[GBN * GBK];

  int tid = threadIdx.x;
  int lane = tid & 63, wave = tid >> 6;
  int wr = (wave >> 1) * 64, wc = (wave & 1) * 64;
  int l15 = lane & 15, lch = lane >> 4;

  // staging: wave w covers rows [w*32, w*32+32), two 16-row instrs each for A and B.
  // lane l -> row r0 + (l>>2), col chunk (l&3)*8; LDS dst = base + l*16B (linear match).
  int srow = wave * 32 + (lane >> 2);
  int scol = (lane & 3) * 8;
  const ushort* gA0 = Fk + (size_t)(bm0 + srow) * DIM + scol;
  const ushort* gA1 = gA0 + (size_t)16 * DIM;
  const ushort* gB0 = Mk + (size_t)(bn0 + srow) * DIM + scol;
  const ushort* gB1 = gB0 + (size_t)16 * DIM;
  ushort* lA0 = As + (wave * 32) * GBK;
  ushort* lA1 = As + (wave * 32 + 16) * GBK;
  ushort* lB0 = Bs + (wave * 32) * GBK;
  ushort* lB1 = Bs + (wave * 32 + 16) * GBK;

  f32x4 acc[4][4];
#pragma unroll
  for (int i = 0; i < 4; ++i)
#pragma unroll
    for (int j = 0; j < 4; ++j) acc[i][j] = (f32x4){0.f, 0.f, 0.f, 0.f};

  for (int kk = 0; kk < DIM; kk += GBK) {
    __syncthreads();  // prior iteration's ds_reads done before overwrite
    gld_lds16(gA0 + kk, lA0);
    gld_lds16(gA1 + kk, lA1);
    gld_lds16(gB0 + kk, lB0);
    gld_lds16(gB1 + kk, lB1);
    __syncthreads();  // compiler drains vmcnt(0) before barrier -> tiles ready

    bf16x8 af[4], bfr[4];
#pragma unroll
    for (int i = 0; i < 4; ++i) {
      af[i] = *reinterpret_cast<const bf16x8*>(As + (wr + i * 16 + l15) * GBK + lch * 8);
      bfr[i] = *reinterpret_cast<const bf16x8*>(Bs + (wc + i * 16 + l15) * GBK + lch * 8);
    }
#pragma unroll
    for (int i = 0; i < 4; ++i)
#pragma unroll
      for (int j = 0; j < 4; ++j)
        acc[i][j] = __builtin_amdgcn_mfma_f32_16x16x32_bf16(af[i], bfr[j], acc[i][j], 0, 0, 0);
  }

  // epilogue: D frag col = lane&15, row = (lane>>4)*4 + reg
  size_t kb = (size_t)k * BATCH;
  int rgrp = lch << 2;
  float fi[4][4];
#pragma unroll
  for (int i = 0; i < 4; ++i)
#pragma unroll
    for (int r = 0; r < 4; ++r)
      fi[i][r] = (float)invF[kb + bm0 + wr + i * 16 + rgrp + r];
#pragma unroll
  for (int j = 0; j < 4; ++j) {
    int c = bn0 + wc + j * 16 + l15;
    float im = (float)invM[(size_t)k * NMEM + c];
#pragma unroll
    for (int i = 0; i < 4; ++i) {
      int rbase = bm0 + wr + i * 16 + rgrp;
#pragma unroll
      for (int r = 0; r < 4; ++r)
        sim[(kb + rbase + r) * NMEM + c] = acc[i][j][r] * fi[i][r] * im;
    }
  }
}

// ---------------- top-k + fp64 refine + softmax scatter + entropy ----------------

__global__ __launch_bounds__(256) void topk_kernel(
    const float* __restrict__ F, const float* __restrict__ M,
    const double* __restrict__ invF, const double* __restrict__ invM,
    const float* __restrict__ sim, float* __restrict__ soft,
    float* __restrict__ ent) {
  int kb = blockIdx.x;
  int k = kb / BATCH;
  int tid = threadIdx.x;
  const float* srow = sim + (size_t)kb * NMEM;
  float* orow = soft + (size_t)kb * NMEM;

  float tv[8]; int ti[8];
#pragma unroll
  for (int j = 0; j < 8; ++j) { tv[j] = -INFINITY; ti[j] = -1; }
  const float4 z4 = make_float4(0.f, 0.f, 0.f, 0.f);
  for (int i = 0; i < NMEM / 1024; ++i) {  // 32 iters, float4
    int n = i * 1024 + tid * 4;
    float4 v = *reinterpret_cast<const float4*>(srow + n);
    *reinterpret_cast<float4*>(orow + n) = z4;  // fused zero-fill
    float vv[4] = {v.x, v.y, v.z, v.w};
#pragma unroll
    for (int c = 0; c < 4; ++c) {
      if (vv[c] > tv[0]) {
        tv[0] = vv[c]; ti[0] = n + c;
#pragma unroll
        for (int j = 0; j < 7; ++j) {
          if (tv[j] > tv[j + 1]) {
            float t = tv[j]; tv[j] = tv[j + 1]; tv[j + 1] = t;
            int q = ti[j]; ti[j] = ti[j + 1]; ti[j + 1] = q;
          }
        }
      }
    }
  }

  __shared__ float sval[2048];
  __shared__ int   sidx[2048];
#pragma unroll
  for (int j = 0; j < 8; ++j) { sval[tid * 8 + j] = tv[j]; sidx[tid * 8 + j] = ti[j]; }
  __syncthreads();

  __shared__ float rv[256]; __shared__ int rp[256];
  __shared__ float cand_v[8]; __shared__ int cand_i[8];
  for (int r = 0; r < 8; ++r) {
    float best = -INFINITY; int bpos = tid * 8;
#pragma unroll
    for (int j = 0; j < 8; ++j) {
      float v = sval[tid * 8 + j];
      if (v > best) { best = v; bpos = tid * 8 + j; }
    }
    rv[tid] = best; rp[tid] = bpos;
    __syncthreads();
    for (int st = 128; st > 0; st >>= 1) {
      if (tid < st && rv[tid + st] > rv[tid]) { rv[tid] = rv[tid + st]; rp[tid] = rp[tid + st]; }
      __syncthreads();
    }
    if (tid == 0) {
      cand_v[r] = rv[0]; cand_i[r] = sidx[rp[0]];
      sval[rp[0]] = -INFINITY;
    }
    __syncthreads();
  }

  // fp64 refinement of the 8 candidates (exact re-ranking at the 5/6 boundary)
  __shared__ double dred[256];
  __shared__ double cval[8];
  const float* fr = F + (size_t)kb * DIM;
  double invf = invF[kb];
  for (int c = 0; c < 8; ++c) {
    const float* mr = M + ((size_t)k * NMEM + cand_i[c]) * DIM;
    double s = 0.0;
    for (int d = tid; d < DIM; d += 256) s += (double)fr[d] * (double)mr[d];
    dred[tid] = s; __syncthreads();
    for (int st = 128; st > 0; st >>= 1) {
      if (tid < st) dred[tid] += dred[tid + st];
      __syncthreads();
    }
    if (tid == 0) cval[c] = dred[0] * invf * invM[(size_t)k * NMEM + cand_i[c]];
    __syncthreads();
  }

  if (tid == 0) {
    int ord[8];
    for (int i = 0; i < 8; ++i) ord[i] = i;
    for (int i = 0; i < 5; ++i) {
      int best = i;
      for (int j = i + 1; j < 8; ++j) {
        float fa = (float)cval[ord[j]], fb = (float)cval[ord[best]];
        bool better = (fa != fb) ? (fa > fb) : (cand_i[ord[j]] < cand_i[ord[best]]);
        if (better) best = j;
      }
      int t = ord[i]; ord[i] = ord[best]; ord[best] = t;
    }
    float v5[5]; int i5[5];
    float vmax = -INFINITY;
    for (int i = 0; i < 5; ++i) {
      v5[i] = cand_v[ord[i]]; i5[i] = cand_i[ord[i]];
      vmax = fmaxf(vmax, v5[i]);
    }
    float e[5], Z = 0.f;
    float xm = vmax / 3.0f;
    for (int i = 0; i < 5; ++i) { e[i] = expf(v5[i] / 3.0f - xm); Z += e[i]; }
    float ent_s = 0.f;
    for (int i = 0; i < 5; ++i) {
      float p = e[i] / Z;
      orow[i5[i]] = p;
      ent_s += p * logf(p);
    }
    float tiny = 1e-8f * logf(1e-8f);
    ent[kb] = -(ent_s + (float)(NMEM - 5) * tiny);
  }
}

// ---------------- entropy weights ----------------

__global__ __launch_bounds__(256) void w_kernel(const float* __restrict__ ent,
                                                float* __restrict__ wout) {
  int k = blockIdx.x; int tid = threadIdx.x;
  float e = ent[k * BATCH + tid];
  float wv = expf(-e);
  __shared__ float red[256];
  red[tid] = wv; __syncthreads();
  for (int st = 128; st > 0; st >>= 1) {
    if (tid < st) red[tid] += red[tid + st];
    __syncthreads();
  }
  float mean = red[0] / (float)BATCH;
  wout[k * BATCH + tid] = wv / (mean + 1e-8f);
}

// ---------------- launch ----------------

extern "C" void kernel_launch(void* const* d_in, const int* in_sizes, int n_in,
                              void* d_out, int out_size, void* d_ws, size_t ws_size,
                              hipStream_t stream) {
  (void)in_sizes; (void)n_in; (void)out_size; (void)ws_size;
  const float* F = (const float*)d_in[0];   // [KP, BATCH, DIM] fp32
  const float* M = (const float*)d_in[1];   // [KP, NMEM, DIM] fp32
  float* out = (float*)d_out;
  size_t simsz = (size_t)KP * BATCH * NMEM;
  float* soft = out;
  float* sim = out + simsz;
  float* wout = out + 2 * simsz;

  // workspace layout (needs ~306 MB; ws is ~2.4 GB per harness poison traffic)
  ushort* Mb = (ushort*)d_ws;                               // KP*NMEM*DIM bf16
  ushort* Fb = Mb + (size_t)KP * NMEM * DIM;                // KP*BATCH*DIM bf16
  double* invM = (double*)(Fb + (size_t)KP * BATCH * DIM);  // KP*NMEM f64
  double* invF = invM + (size_t)KP * NMEM;                  // KP*BATCH f64
  float* ent = (float*)(invF + KP * BATCH);                 // KP*BATCH f32

  prep_kernel<<<KP * BATCH / 4, 256, 0, stream>>>(F, Fb, invF, KP * BATCH);
  prep_kernel<<<KP * NMEM / 4, 256, 0, stream>>>(M, Mb, invM, KP * NMEM);
  gemm_kernel<<<dim3(NMEM / GBN, BATCH / GBM, KP), 256, 0, stream>>>(Fb, Mb, invF, invM, sim);
  topk_kernel<<<KP * BATCH, 256, 0, stream>>>(F, M, invF, invM, sim, soft, ent);
  w_kernel<<<KP, 256, 0, stream>>>(ent, wout);
}

// Round 4
// 470.277 us; speedup vs baseline: 3.1290x; 1.0416x over previous
//
#include <hip/hip_runtime.h>
#include <math.h>

#define KP 6
#define BATCH 256
#define DIM 768
#define NMEM 32768
#define NXBLK (NMEM / 128)   // col-blocks per row = 256
#define NROWS (KP * BATCH)   // 1536

typedef __attribute__((ext_vector_type(8))) short bf16x8;
typedef __attribute__((ext_vector_type(4))) float f32x4;

__device__ inline uint bf16rne(float x) {
  uint u = __builtin_bit_cast(uint, x);
  return (u + 0x7fffu + ((u >> 16) & 1u)) >> 16;
}
__device__ inline uint pk2(float lo, float hi) {
  return bf16rne(lo) | (bf16rne(hi) << 16);
}
// XOR swizzle: flips 16B-unit bits with row bits 1-2 (row stride 64B). Involution.
__device__ inline int swz(int b) { return b ^ (((b >> 7) & 3) << 4); }

__device__ inline void gld_lds16(const ushort* g, ushort* l) {
  __builtin_amdgcn_global_load_lds(
      (const __attribute__((address_space(1))) void*)g,
      (__attribute__((address_space(3))) void*)l, 16, 0, 0);
}

// ---------------- prep: fp64 inv-norms + bf16 copies ----------------

__global__ __launch_bounds__(256) void prep_kernel(const float* __restrict__ X,
                                                   ushort* __restrict__ Xb,
                                                   double* __restrict__ invX,
                                                   int nrows) {
  int wid = threadIdx.x >> 6, lane = threadIdx.x & 63;
  int row = blockIdx.x * 4 + wid;
  if (row >= nrows) return;
  const float* x = X + (size_t)row * DIM;
  ushort* xb = Xb + (size_t)row * DIM;
  double s = 0.0;
#pragma unroll
  for (int i = 0; i < 3; ++i) {
    int d = i * 256 + lane * 4;
    float4 v = *reinterpret_cast<const float4*>(x + d);
    s += (double)v.x * v.x + (double)v.y * v.y;
    s += (double)v.z * v.z + (double)v.w * v.w;
    uint2 p; p.x = pk2(v.x, v.y); p.y = pk2(v.z, v.w);
    *reinterpret_cast<uint2*>(xb + d) = p;
  }
  for (int off = 32; off > 0; off >>= 1) s += __shfl_down(s, off);
  if (lane == 0) invX[row] = 1.0 / fmax(sqrt(s), 1e-12);
}

// ---------------- bf16 MFMA GEMM + fused per-block top-4 partials ----------
// 128x128 tile, BK=32, 4 waves (2x2). Swizzled staging via pre-swizzled
// global source (LDS dest stays linear per gload_lds rules), swizzled reads.

#define GBM 128
#define GBN 128
#define GBK 32
#define CHS 132  // epilogue chunk row stride in floats (132*4=528 ≡ 0 mod 16)

__global__ __launch_bounds__(256) void gemm_kernel(
    const ushort* __restrict__ Fb, const ushort* __restrict__ Mb,
    const double* __restrict__ invF, const double* __restrict__ invM,
    float* __restrict__ sim, float2* __restrict__ P) {
  int k = blockIdx.z;
  int bm0 = blockIdx.x * GBM;   // mtile fastest -> pair shares B-tile (L2/LLC)
  int bn0 = blockIdx.y * GBN;
  const ushort* Fk = Fb + (size_t)k * BATCH * DIM;
  const ushort* Mk = Mb + (size_t)k * NMEM * DIM;

  __shared__ __align__(16) char smem[64 * CHS * 4];  // 33792 B
  ushort* As = (ushort*)smem;            // 8192 B
  ushort* Bs = (ushort*)(smem + 8192);   // 8192 B
  float* chunk = (float*)smem;           // epilogue reuse (64 x CHS)

  int tid = threadIdx.x;
  int lane = tid & 63, wave = tid >> 6;
  int wr = (wave >> 1) * 64, wc = (wave & 1) * 64;
  int l15 = lane & 15, lch = lane >> 4;

  // staging: lane l -> row r0+(l>>2); global col chunk PRE-SWIZZLED so linear
  // LDS ends up XOR-swizzled: c_g = (l&3) ^ ((l>>3)&3)   [(r0>>1)&3 == 0 always]
  int srow = wave * 32 + (lane >> 2);
  int scol = ((lane & 3) ^ ((lane >> 3) & 3)) * 8;
  const ushort* gA0 = Fk + (size_t)(bm0 + srow) * DIM + scol;
  const ushort* gA1 = gA0 + (size_t)16 * DIM;
  const ushort* gB0 = Mk + (size_t)(bn0 + srow) * DIM + scol;
  const ushort* gB1 = gB0 + (size_t)16 * DIM;
  ushort* lA0 = As + (wave * 32) * GBK;
  ushort* lA1 = As + (wave * 32 + 16) * GBK;
  ushort* lB0 = Bs + (wave * 32) * GBK;
  ushort* lB1 = Bs + (wave * 32 + 16) * GBK;

  // swizzled fragment byte-offsets (K-invariant)
  int aoff[4], boff[4];
#pragma unroll
  for (int i = 0; i < 4; ++i) {
    aoff[i] = swz((wr + i * 16 + l15) * 64 + lch * 16);
    boff[i] = swz((wc + i * 16 + l15) * 64 + lch * 16);
  }

  f32x4 acc[4][4];
#pragma unroll
  for (int i = 0; i < 4; ++i)
#pragma unroll
    for (int j = 0; j < 4; ++j) acc[i][j] = (f32x4){0.f, 0.f, 0.f, 0.f};

  for (int kk = 0; kk < DIM; kk += GBK) {
    __syncthreads();
    gld_lds16(gA0 + kk, lA0);
    gld_lds16(gA1 + kk, lA1);
    gld_lds16(gB0 + kk, lB0);
    gld_lds16(gB1 + kk, lB1);
    __syncthreads();

    bf16x8 af[4], bfr[4];
#pragma unroll
    for (int i = 0; i < 4; ++i) {
      af[i] = *reinterpret_cast<const bf16x8*>((char*)As + aoff[i]);
      bfr[i] = *reinterpret_cast<const bf16x8*>((char*)Bs + boff[i]);
    }
#pragma unroll
    for (int i = 0; i < 4; ++i)
#pragma unroll
      for (int j = 0; j < 4; ++j)
        acc[i][j] = __builtin_amdgcn_mfma_f32_16x16x32_bf16(af[i], bfr[j], acc[i][j], 0, 0, 0);
  }

  // ---------- epilogue: scale, LDS chunk, coalesced sim store, top-4 ----------
  size_t kb = (size_t)k * BATCH;
  int rgrp = lch << 2;
  float fi[4][4];
#pragma unroll
  for (int i = 0; i < 4; ++i)
#pragma unroll
    for (int r = 0; r < 4; ++r)
      fi[i][r] = (float)invF[kb + bm0 + wr + i * 16 + rgrp + r];
  float im[4];
#pragma unroll
  for (int j = 0; j < 4; ++j)
    im[j] = (float)invM[(size_t)k * NMEM + bn0 + wc + j * 16 + l15];

  for (int h = 0; h < 2; ++h) {
    __syncthreads();  // chunk buffer free (staging or previous chunk done)
    if (wr == h * 64) {
#pragma unroll
      for (int i = 0; i < 4; ++i)
#pragma unroll
        for (int j = 0; j < 4; ++j)
#pragma unroll
          for (int r = 0; r < 4; ++r) {
            int rc = i * 16 + rgrp + r;        // 0..63
            int cc = wc + j * 16 + l15;        // 0..127
            chunk[rc * CHS + cc] = acc[i][j][r] * fi[i][r] * im[j];
          }
    }
    __syncthreads();
    int grow0 = bm0 + h * 64;
    // coalesced sim store: 2048 float4 units / 256 threads = 8 passes
#pragma unroll
    for (int uu = 0; uu < 8; ++uu) {
      int u = uu * 256 + tid;
      int rc = u >> 5, cu = u & 31;
      f32x4 v = *reinterpret_cast<const f32x4*>(chunk + rc * CHS + cu * 4);
      *reinterpret_cast<f32x4*>(sim + (kb + grow0 + rc) * NMEM + bn0 + cu * 4) = v;
    }
    // scan: 4 threads/row, cols q+4j (2-way banks)
    int rc = tid >> 2, q = tid & 3;
    float v4[4] = {-INFINITY, -INFINITY, -INFINITY, -INFINITY};
    int i4[4] = {0, 0, 0, 0};
#pragma unroll
    for (int j = 0; j < 32; ++j) {
      int cc = q + 4 * j;
      float v = chunk[rc * CHS + cc];
      if (v > v4[3]) {
        v4[3] = v; i4[3] = cc;
        if (v4[3] > v4[2]) { float t = v4[3]; v4[3] = v4[2]; v4[2] = t; int s = i4[3]; i4[3] = i4[2]; i4[2] = s; }
        if (v4[2] > v4[1]) { float t = v4[2]; v4[2] = v4[1]; v4[1] = t; int s = i4[2]; i4[2] = i4[1]; i4[1] = s; }
        if (v4[1] > v4[0]) { float t = v4[1]; v4[1] = v4[0]; v4[0] = t; int s = i4[1]; i4[1] = i4[0]; i4[0] = s; }
      }
    }
    __syncthreads();  // all scans done; chunk vals dead -> reuse as list scratch
    float2* lists = (float2*)chunk;  // [64 rows][4 q][4 slots]
#pragma unroll
    for (int s = 0; s < 4; ++s)
      lists[(rc * 4 + q) * 4 + s] = make_float2(v4[s], __builtin_bit_cast(float, i4[s]));
    __syncthreads();
    if (q == 0) {
      float mv[4] = {-INFINITY, -INFINITY, -INFINITY, -INFINITY};
      int mi[4] = {0, 0, 0, 0};
#pragma unroll
      for (int e = 0; e < 16; ++e) {
        float2 p = lists[rc * 16 + e];
        float v = p.x; int ix = __builtin_bit_cast(int, p.y);
        if (v > mv[3]) {
          mv[3] = v; mi[3] = ix;
          if (mv[3] > mv[2]) { float t = mv[3]; mv[3] = mv[2]; mv[2] = t; int s = mi[3]; mi[3] = mi[2]; mi[2] = s; }
          if (mv[2] > mv[1]) { float t = mv[2]; mv[2] = mv[1]; mv[1] = t; int s = mi[2]; mi[2] = mi[1]; mi[1] = s; }
          if (mv[1] > mv[0]) { float t = mv[1]; mv[1] = mv[0]; mv[0] = t; int s = mi[1]; mi[1] = mi[0]; mi[0] = s; }
        }
      }
      float2* Prow = P + ((size_t)(kb + grow0 + rc) * NXBLK + blockIdx.y) * 4;
#pragma unroll
      for (int s = 0; s < 4; ++s)
        Prow[s] = make_float2(mv[s], __builtin_bit_cast(float, mi[s] + bn0));
    }
  }
}

// ---------------- merge partials + fp64 refine + softmax + entropy ----------

__global__ __launch_bounds__(256) void merge_kernel(
    const float* __restrict__ F, const float* __restrict__ M,
    const double* __restrict__ invF, const double* __restrict__ invM,
    const float2* __restrict__ P, float* __restrict__ soft,
    float* __restrict__ ent) {
  int kb = blockIdx.x;  // 0..1535
  int k = kb / BATCH;
  int tid = threadIdx.x;
  float* orow = soft + (size_t)kb * NMEM;

  __shared__ float sval[1024];
  __shared__ int   sidx[1024];
  const float2* Prow = P + (size_t)kb * NXBLK * 4;
#pragma unroll
  for (int j = 0; j < 4; ++j) {
    float2 e = Prow[tid * 4 + j];
    sval[tid * 4 + j] = e.x;
    sidx[tid * 4 + j] = __builtin_bit_cast(int, e.y);
  }
  // zero-fill soft row (201 MB total across grid)
  const float4 z4 = make_float4(0.f, 0.f, 0.f, 0.f);
#pragma unroll
  for (int i = 0; i < 32; ++i)
    *reinterpret_cast<float4*>(orow + i * 1024 + tid * 4) = z4;
  __syncthreads();

  __shared__ float rv[256]; __shared__ int rp[256];
  __shared__ float cand_v[8]; __shared__ int cand_i[8];
  for (int r = 0; r < 8; ++r) {
    float best = -INFINITY; int bpos = tid * 4;
#pragma unroll
    for (int j = 0; j < 4; ++j) {
      float v = sval[tid * 4 + j];
      if (v > best) { best = v; bpos = tid * 4 + j; }
    }
    rv[tid] = best; rp[tid] = bpos;
    __syncthreads();
    for (int st = 128; st > 0; st >>= 1) {
      if (tid < st && rv[tid + st] > rv[tid]) { rv[tid] = rv[tid + st]; rp[tid] = rp[tid + st]; }
      __syncthreads();
    }
    if (tid == 0) {
      cand_v[r] = rv[0]; cand_i[r] = sidx[rp[0]];
      sval[rp[0]] = -INFINITY;
    }
    __syncthreads();
  }

  // fp64 refinement of the 8 candidates (exact re-ranking at the 5/6 boundary)
  __shared__ double dred[256];
  __shared__ double cval[8];
  const float* fr = F + (size_t)kb * DIM;
  double invf = invF[kb];
  for (int c = 0; c < 8; ++c) {
    const float* mr = M + ((size_t)k * NMEM + cand_i[c]) * DIM;
    double s = 0.0;
    for (int d = tid; d < DIM; d += 256) s += (double)fr[d] * (double)mr[d];
    dred[tid] = s; __syncthreads();
    for (int st = 128; st > 0; st >>= 1) {
      if (tid < st) dred[tid] += dred[tid + st];
      __syncthreads();
    }
    if (tid == 0) cval[c] = dred[0] * invf * invM[(size_t)k * NMEM + cand_i[c]];
    __syncthreads();
  }

  if (tid == 0) {
    int ord[8];
    for (int i = 0; i < 8; ++i) ord[i] = i;
    for (int i = 0; i < 5; ++i) {
      int best = i;
      for (int j = i + 1; j < 8; ++j) {
        float fa = (float)cval[ord[j]], fb = (float)cval[ord[best]];
        bool better = (fa != fb) ? (fa > fb) : (cand_i[ord[j]] < cand_i[ord[best]]);
        if (better) best = j;
      }
      int t = ord[i]; ord[i] = ord[best]; ord[best] = t;
    }
    float v5[5]; int i5[5];
    float vmax = -INFINITY;
    for (int i = 0; i < 5; ++i) {
      v5[i] = cand_v[ord[i]]; i5[i] = cand_i[ord[i]];
      vmax = fmaxf(vmax, v5[i]);
    }
    float e[5], Z = 0.f;
    float xm = vmax / 3.0f;
    for (int i = 0; i < 5; ++i) { e[i] = expf(v5[i] / 3.0f - xm); Z += e[i]; }
    float ent_s = 0.f;
    for (int i = 0; i < 5; ++i) {
      float p = e[i] / Z;
      orow[i5[i]] = p;
      ent_s += p * logf(p);
    }
    float tiny = 1e-8f * logf(1e-8f);
    ent[kb] = -(ent_s + (float)(NMEM - 5) * tiny);
  }
}

// ---------------- entropy weights ----------------

__global__ __launch_bounds__(256) void w_kernel(const float* __restrict__ ent,
                                                float* __restrict__ wout) {
  int k = blockIdx.x; int tid = threadIdx.x;
  float e = ent[k * BATCH + tid];
  float wv = expf(-e);
  __shared__ float red[256];
  red[tid] = wv; __syncthreads();
  for (int st = 128; st > 0; st >>= 1) {
    if (tid < st) red[tid] += red[tid + st];
    __syncthreads();
  }
  float mean = red[0] / (float)BATCH;
  wout[k * BATCH + tid] = wv / (mean + 1e-8f);
}

// ---------------- launch ----------------

extern "C" void kernel_launch(void* const* d_in, const int* in_sizes, int n_in,
                              void* d_out, int out_size, void* d_ws, size_t ws_size,
                              hipStream_t stream) {
  (void)in_sizes; (void)n_in; (void)out_size; (void)ws_size;
  const float* F = (const float*)d_in[0];   // [KP, BATCH, DIM] fp32
  const float* M = (const float*)d_in[1];   // [KP, NMEM, DIM] fp32
  float* out = (float*)d_out;
  size_t simsz = (size_t)KP * BATCH * NMEM;
  float* soft = out;
  float* sim = out + simsz;
  float* wout = out + 2 * simsz;

  // workspace layout (~320 MB of the ~2.4 GB ws)
  ushort* Mb = (ushort*)d_ws;                               // KP*NMEM*DIM bf16
  ushort* Fb = Mb + (size_t)KP * NMEM * DIM;                // KP*BATCH*DIM bf16
  double* invM = (double*)(Fb + (size_t)KP * BATCH * DIM);  // KP*NMEM f64
  double* invF = invM + (size_t)KP * NMEM;                  // KP*BATCH f64
  float* ent = (float*)(invF + KP * BATCH);                 // KP*BATCH f32
  float2* P = (float2*)(ent + NROWS);                       // NROWS*NXBLK*4 float2

  prep_kernel<<<KP * BATCH / 4, 256, 0, stream>>>(F, Fb, invF, KP * BATCH);
  prep_kernel<<<KP * NMEM / 4, 256, 0, stream>>>(M, Mb, invM, KP * NMEM);
  gemm_kernel<<<dim3(BATCH / GBM, NMEM / GBN, KP), 256, 0, stream>>>(Fb, Mb, invF, invM, sim, P);
  merge_kernel<<<NROWS, 256, 0, stream>>>(F, M, invF, invM, P, soft, ent);
  w_kernel<<<KP, 256, 0, stream>>>(ent, wout);
}